// Round 15
// baseline (1229.516 us; speedup 1.0000x reference)
//
#include <hip/hip_runtime.h>

typedef __bf16 bf16x2 __attribute__((ext_vector_type(2)));
typedef __bf16 bf16x4 __attribute__((ext_vector_type(4)));
typedef __bf16 bf16x8 __attribute__((ext_vector_type(8)));
typedef float f32x4 __attribute__((ext_vector_type(4)));

#define CSR_CHUNKS 256  // edge stripes per dst-range in partitioned CSR build

__device__ __forceinline__ void gload16(const __bf16* g, __bf16* l) {
    __builtin_amdgcn_global_load_lds((const __attribute__((address_space(1))) void*)g,
                                     (__attribute__((address_space(3))) void*)l, 16, 0, 0);
}

// ---------------- CSR build (XCD-partitioned by dst range) ----------------
__global__ __launch_bounds__(256)
void hist_part_kernel(const int* __restrict__ dst, int* __restrict__ deg, int E, int N) {
    const int r = blockIdx.x & 7;
    const int chunk = blockIdx.x >> 3;
    const int RS = (N + 7) >> 3;
    const int lo = r * RS;
    const int hi = min(lo + RS, N);
    const int stride = CSR_CHUNKS * 256;
    for (int i = chunk * 256 + threadIdx.x; i < E; i += stride) {
        int d = dst[i];
        if (d >= lo && d < hi) atomicAdd(&deg[d], 1);
    }
}

__global__ __launch_bounds__(256)
void scatter_part_kernel(const int* __restrict__ src, const int* __restrict__ dst,
                         int* __restrict__ cursor, int* __restrict__ colsrc, int E, int N) {
    const int r = blockIdx.x & 7;
    const int chunk = blockIdx.x >> 3;
    const int RS = (N + 7) >> 3;
    const int lo = r * RS;
    const int hi = min(lo + RS, N);
    const int stride = CSR_CHUNKS * 256;
    for (int i = chunk * 256 + threadIdx.x; i < E; i += stride) {
        int d = dst[i];
        if (d >= lo && d < hi) {
            int p = atomicAdd(&cursor[d], 1);
            colsrc[p] = src[i];
        }
    }
}

// hierarchical exclusive scan of deg -> rowptr/cursor
__global__ __launch_bounds__(256)
void blocksum_kernel(const int* __restrict__ deg, int* __restrict__ bsum, int n) {
    __shared__ int red[256];
    int i = blockIdx.x * 256 + threadIdx.x;
    red[threadIdx.x] = (i < n) ? deg[i] : 0;
    __syncthreads();
    for (int off = 128; off > 0; off >>= 1) {
        if (threadIdx.x < off) red[threadIdx.x] += red[threadIdx.x + off];
        __syncthreads();
    }
    if (threadIdx.x == 0) bsum[blockIdx.x] = red[0];
}

__global__ __launch_bounds__(256)
void scanb_kernel(int* __restrict__ bsum, int nb) {
    __shared__ int s[256];
    int t = threadIdx.x;
    s[t] = (t < nb) ? bsum[t] : 0;
    __syncthreads();
    for (int off = 1; off < 256; off <<= 1) {
        int v = (t >= off) ? s[t - off] : 0;
        __syncthreads();
        s[t] += v;
        __syncthreads();
    }
    if (t < nb) bsum[t] = (t == 0) ? 0 : s[t - 1];
}

__global__ __launch_bounds__(256)
void scanw_kernel(const int* __restrict__ deg, const int* __restrict__ bsum,
                  int* __restrict__ rowptr, int* __restrict__ cursor, int n) {
    __shared__ int s[256];
    int b = blockIdx.x, t = threadIdx.x;
    int i = b * 256 + t;
    int d = (i < n) ? deg[i] : 0;
    s[t] = d;
    __syncthreads();
    for (int off = 1; off < 256; off <<= 1) {
        int v = (t >= off) ? s[t - off] : 0;
        __syncthreads();
        s[t] += v;
        __syncthreads();
    }
    int incl = s[t];
    int base = bsum[b];
    if (i < n) {
        int r = base + incl - d;
        rowptr[i] = r;
        cursor[i] = r;
        if (i == n - 1) rowptr[n] = base + incl;
    }
}

// ---------------- dtype convert / weight prep ----------------
__global__ void f32_to_bf16_kernel(const float* __restrict__ in, __bf16* __restrict__ out, int n4) {
    int i = blockIdx.x * 256 + threadIdx.x;
    if (i < n4) {
        float4 f = ((const float4*)in)[i];
        bf16x4 o;
        o[0] = (__bf16)f.x; o[1] = (__bf16)f.y; o[2] = (__bf16)f.z; o[3] = (__bf16)f.w;
        ((bf16x4*)out)[i] = o;
    }
}

__global__ void wprep_kernel(const float* __restrict__ in, __bf16* __restrict__ out, int kbits) {
    int idx = blockIdx.x * 256 + threadIdx.x;
    int K = 1 << kbits;
    if (idx < (512 << kbits)) {
        int k = idx & (K - 1);
        int n = idx >> kbits;
        out[idx] = (__bf16)in[k * 512 + n];
    }
}

// ---------------- aggregation ----------------
template<int F> struct VecT;
template<> struct VecT<2> { using T = bf16x2; };
template<> struct VecT<4> { using T = bf16x4; };
template<> struct VecT<8> { using T = bf16x8; };

template<int F, int U, int STR>
__global__ __launch_bounds__(256)
void agg_kernel(const __bf16* __restrict__ xb, const int* __restrict__ rowptr,
                const int* __restrict__ colsrc, __bf16* __restrict__ h, int n, int colbase) {
    const int node = blockIdx.x * 4 + (threadIdx.x >> 6);
    if (node >= n) return;
    const int lane = threadIdx.x & 63;
    using V = typename VecT<F>::T;

    const __bf16* xl = xb + colbase + lane * F;

    float acc[F];
    {
        V v = *(const V*)(xl + (size_t)node * STR);
        #pragma unroll
        for (int i = 0; i < F; i++) acc[i] = (float)v[i];
    }

    int e   = __builtin_amdgcn_readfirstlane(rowptr[node]);
    int end = __builtin_amdgcn_readfirstlane(rowptr[node + 1]);

    for (; e + U <= end; e += U) {
        int s[U];
        #pragma unroll
        for (int j = 0; j < U; j++) s[j] = colsrc[e + j];
        V v[U];
        #pragma unroll
        for (int j = 0; j < U; j++) v[j] = *(const V*)(xl + (size_t)s[j] * STR);
        #pragma unroll
        for (int j = 0; j < U; j++)
            #pragma unroll
            for (int i = 0; i < F; i++) acc[i] += (float)v[j][i];
    }
    if constexpr (U > 4) {
        for (; e + 4 <= end; e += 4) {
            int s[4];
            #pragma unroll
            for (int j = 0; j < 4; j++) s[j] = colsrc[e + j];
            V v[4];
            #pragma unroll
            for (int j = 0; j < 4; j++) v[j] = *(const V*)(xl + (size_t)s[j] * STR);
            #pragma unroll
            for (int j = 0; j < 4; j++)
                #pragma unroll
                for (int i = 0; i < F; i++) acc[i] += (float)v[j][i];
        }
    }
    for (; e < end; e++) {
        int s0 = colsrc[e];
        V v = *(const V*)(xl + (size_t)s0 * STR);
        #pragma unroll
        for (int i = 0; i < F; i++) acc[i] += (float)v[i];
    }

    __bf16* out = h + colbase + (size_t)node * STR + lane * F;
    V o;
    #pragma unroll
    for (int i = 0; i < F; i++) o[i] = (__bf16)acc[i];
    *(V*)out = o;
}

// ---------------- fused layer: xb_tile = relu(h_tile@w1 + b1)@w2 + b2 ----------------
// One 512-thread block per 64-row tile; covers all N=512 both phases.
// Phase 1: h@w1 (K1) with DMA staging (gemmF-proven), epilogue writes u (bias+relu,
//   bf16) into 16 swizzled LDS k-planes (2056-elem stride: +8 pad rotates banks).
// Phase 2: u@w2 (K=512) with A-reads PURE LDS (plane t, same verified swizzle:
//   key=(row>>1)&3=(mlane>>1)&3 on both write and read sides), only B staged
//   (4 DMA/wave, counted vmcnt(4), never 0 in steady state).
// Saves per layer: u HBM write (51MB) + read (51MB) + one launch + all of
// GEMM2's A-staging latency. LDS 136.2KB static (96KB proven in R12).
template<int DUMMY>
__global__ __launch_bounds__(512, 1)
void layer_kernel(const __bf16* __restrict__ A, const __bf16* __restrict__ B1t,
                  const float* __restrict__ b1, const __bf16* __restrict__ B2t,
                  const float* __restrict__ b2, __bf16* __restrict__ Out,
                  int M, int K1) {
    __shared__ __bf16 smem[69760];            // 139,520 B
    __bf16* const U   = smem;                 // 16 planes x 2056 elems (u, swizzled)
    __bf16* const sA0 = smem + 32896;         // phase-1 A dbuf (2048 each)
    __bf16* const sA1 = smem + 34944;
    __bf16* const sB0 = smem + 36992;         // B dbuf (16384 each)
    __bf16* const sB1 = smem + 53376;
    float* const  tp  = (float*)(smem + 36992);  // 16x516 f32 transpose scratch (aliases B dbuf)

    const int tid = threadIdx.x;
    const int lane = tid & 63;
    const int wid = tid >> 6;        // 0..7
    const int mlane = lane & 15;
    const int quad = lane >> 4;
    const int rowBase = blockIdx.x * 64;

    const int swzc = (((lane & 3) ^ ((lane >> 3) & 3)) << 3);

    // phase-1 A staging (waves 0..3): wave w stages rows [w*16, w*16+16); clamped
    const int aRow = rowBase + wid * 16 + (lane >> 2);
    const int aRowC = (aRow < M) ? aRow : (M - 1);
    const __bf16* aSrc = A + (size_t)aRowC * K1 + swzc;
    // B staging (all 8 waves): wave w stages rows [w*64, w*64+64) of 512
    const int bRow = wid * 64 + (lane >> 2);
    const __bf16* bSrc1 = B1t + (size_t)bRow * K1 + swzc;
    const __bf16* bSrc2 = B2t + (size_t)bRow * 512 + swzc;

    const int rkey = (mlane >> 1) & 3;
    const int base_r = mlane * 32 + ((quad ^ rkey) << 3);

    f32x4 acc[4][4];
    #pragma unroll
    for (int i = 0; i < 4; i++)
        #pragma unroll
        for (int j = 0; j < 4; j++) acc[i][j] = f32x4{0.f, 0.f, 0.f, 0.f};

    auto stage1 = [&](__bf16* bufA, __bf16* bufB, int k0) {
        if (wid < 4) gload16(aSrc + k0, bufA + wid * 512);
        #pragma unroll
        for (int j = 0; j < 4; j++)
            gload16(bSrc1 + (size_t)j * 16 * K1 + k0, bufB + wid * 2048 + j * 512);
    };
    auto wait1 = [&]() {
        if (wid < 4) { asm volatile("s_waitcnt vmcnt(5)" ::: "memory"); }
        else         { asm volatile("s_waitcnt vmcnt(4)" ::: "memory"); }
    };
    auto stage2 = [&](__bf16* bufB, int k0) {
        #pragma unroll
        for (int j = 0; j < 4; j++)
            gload16(bSrc2 + (size_t)j * 16 * 512 + k0, bufB + wid * 2048 + j * 512);
    };
    auto computeAB = [&](const __bf16* bufA, const __bf16* bufB) {
        bf16x8 aF[4], bF[4];
        #pragma unroll
        for (int mt = 0; mt < 4; mt++)
            aF[mt] = *(const bf16x8*)(bufA + mt * 512 + base_r);
        #pragma unroll
        for (int nt = 0; nt < 4; nt++)
            bF[nt] = *(const bf16x8*)(bufB + wid * 2048 + nt * 512 + base_r);
        #pragma unroll
        for (int mt = 0; mt < 4; mt++)
            #pragma unroll
            for (int nt = 0; nt < 4; nt++)
                acc[mt][nt] = __builtin_amdgcn_mfma_f32_16x16x32_bf16(aF[mt], bF[nt], acc[mt][nt], 0, 0, 0);
    };
    auto computeU = [&](int t, const __bf16* bufB) {   // phase-2: A from U plane t
        const __bf16* pA = U + (size_t)t * 2056;
        bf16x8 aF[4], bF[4];
        #pragma unroll
        for (int mt = 0; mt < 4; mt++)
            aF[mt] = *(const bf16x8*)(pA + mt * 512 + base_r);
        #pragma unroll
        for (int nt = 0; nt < 4; nt++)
            bF[nt] = *(const bf16x8*)(bufB + wid * 2048 + nt * 512 + base_r);
        #pragma unroll
        for (int mt = 0; mt < 4; mt++)
            #pragma unroll
            for (int nt = 0; nt < 4; nt++)
                acc[mt][nt] = __builtin_amdgcn_mfma_f32_16x16x32_bf16(aF[mt], bF[nt], acc[mt][nt], 0, 0, 0);
    };

    // ================= phase 1: h @ w1 =================
    const int nt1 = K1 >> 5;
    stage1(sA0, sB0, 0);
    __builtin_amdgcn_sched_barrier(0);
    stage1(sA1, sB1, 32);
    wait1();
    __builtin_amdgcn_sched_barrier(0);
    __builtin_amdgcn_s_barrier();
    __builtin_amdgcn_sched_barrier(0);

    int cur = 0;
    for (int t = 0; t < nt1; ++t) {
        __bf16* cA = cur ? sA1 : sA0;
        __bf16* cB = cur ? sB1 : sB0;
        computeAB(cA, cB);
        if (t + 1 < nt1) {
            __builtin_amdgcn_s_barrier();
            __builtin_amdgcn_sched_barrier(0);
            if (t + 2 < nt1) {
                stage1(cA, cB, (t + 2) << 5);
                wait1();
            } else {
                asm volatile("s_waitcnt vmcnt(0)" ::: "memory");
            }
            __builtin_amdgcn_sched_barrier(0);
            __builtin_amdgcn_s_barrier();
            __builtin_amdgcn_sched_barrier(0);
            cur ^= 1;
        }
    }

    // ---- phase-1 epilogue: acc -> (bias+relu) -> u into swizzled LDS planes ----
    {
        float bv[4];
        #pragma unroll
        for (int nt = 0; nt < 4; nt++) bv[nt] = b1[wid * 64 + nt * 16 + mlane];

        const int erow = tid >> 5;          // 0..15
        const int ecg = tid & 31;           // col-group of 16 (32 groups)
        #pragma unroll
        for (int mt = 0; mt < 4; mt++) {
            __syncthreads();                 // tp aliases B dbuf: all K-loop reads done / prev reads done
            #pragma unroll
            for (int nt = 0; nt < 4; nt++) {
                #pragma unroll
                for (int r = 0; r < 4; r++) {
                    float v = fmaxf(acc[mt][nt][r] + bv[nt], 0.f);
                    tp[(quad * 4 + r) * 516 + wid * 64 + nt * 16 + mlane] = v;
                }
            }
            __syncthreads();
            const float* rp = tp + erow * 516 + ecg * 16;
            f32x4 a = *(const f32x4*)(rp);
            f32x4 b = *(const f32x4*)(rp + 4);
            f32x4 c = *(const f32x4*)(rp + 8);
            f32x4 d = *(const f32x4*)(rp + 12);
            bf16x8 o0, o1;
            #pragma unroll
            for (int j = 0; j < 4; j++) { o0[j] = (__bf16)a[j]; o0[4 + j] = (__bf16)b[j]; }
            #pragma unroll
            for (int j = 0; j < 4; j++) { o1[j] = (__bf16)c[j]; o1[4 + j] = (__bf16)d[j]; }
            const int r64 = mt * 16 + erow;          // u row 0..63
            const int key = (r64 >> 1) & 3;
            const int p = ecg >> 1;                   // plane 0..15
            const int c0 = (ecg & 1) << 1;            // chunk 0 or 2
            __bf16* up = U + (size_t)p * 2056 + r64 * 32;
            *(bf16x8*)(up + ((c0 ^ key) << 3)) = o0;
            *(bf16x8*)(up + (((c0 + 1) ^ key) << 3)) = o1;
        }
        __syncthreads();                     // U complete; tp reads done before B dbuf reuse
    }

    // ================= phase 2: u @ w2 (A in LDS) =================
    #pragma unroll
    for (int i = 0; i < 4; i++)
        #pragma unroll
        for (int j = 0; j < 4; j++) acc[i][j] = f32x4{0.f, 0.f, 0.f, 0.f};

    stage2(sB0, 0);
    __builtin_amdgcn_sched_barrier(0);
    stage2(sB1, 32);
    asm volatile("s_waitcnt vmcnt(4)" ::: "memory");
    __builtin_amdgcn_sched_barrier(0);
    __builtin_amdgcn_s_barrier();
    __builtin_amdgcn_sched_barrier(0);

    cur = 0;
    for (int t = 0; t < 16; ++t) {
        __bf16* cB = cur ? sB1 : sB0;
        computeU(t, cB);
        if (t + 1 < 16) {
            __builtin_amdgcn_s_barrier();
            __builtin_amdgcn_sched_barrier(0);
            if (t + 2 < 16) {
                stage2(cB, (t + 2) << 5);
                asm volatile("s_waitcnt vmcnt(4)" ::: "memory");
            } else {
                asm volatile("s_waitcnt vmcnt(0)" ::: "memory");
            }
            __builtin_amdgcn_sched_barrier(0);
            __builtin_amdgcn_s_barrier();
            __builtin_amdgcn_sched_barrier(0);
            cur ^= 1;
        }
    }

    // ---- phase-2 epilogue: acc + b2 -> coalesced bf16x8 stores ----
    {
        float bv[4];
        #pragma unroll
        for (int nt = 0; nt < 4; nt++) bv[nt] = b2[wid * 64 + nt * 16 + mlane];

        const int erow = tid >> 5;
        const int ecg = tid & 31;
        #pragma unroll
        for (int mt = 0; mt < 4; mt++) {
            __syncthreads();
            #pragma unroll
            for (int nt = 0; nt < 4; nt++) {
                #pragma unroll
                for (int r = 0; r < 4; r++)
                    tp[(quad * 4 + r) * 516 + wid * 64 + nt * 16 + mlane] = acc[mt][nt][r] + bv[nt];
            }
            __syncthreads();
            int gr = rowBase + mt * 16 + erow;
            if (gr < M) {
                const float* rp = tp + erow * 516 + ecg * 16;
                f32x4 a = *(const f32x4*)(rp);
                f32x4 b = *(const f32x4*)(rp + 4);
                f32x4 c = *(const f32x4*)(rp + 8);
                f32x4 d = *(const f32x4*)(rp + 12);
                bf16x8 o0, o1;
                #pragma unroll
                for (int j = 0; j < 4; j++) { o0[j] = (__bf16)a[j]; o0[4 + j] = (__bf16)b[j]; }
                #pragma unroll
                for (int j = 0; j < 4; j++) { o1[j] = (__bf16)c[j]; o1[4 + j] = (__bf16)d[j]; }
                __bf16* op = Out + (size_t)gr * 512 + ecg * 16;
                *(bf16x8*)op = o0;
                *(bf16x8*)(op + 8) = o1;
            }
        }
    }
}

// ---------------- paired-panel GEMM (head: AMODE 1 gather-A) ----------------
template<int AMODE, bool RELU>
__global__ __launch_bounds__(256, 3)
void gemm_kernel(const __bf16* __restrict__ A, const __bf16* __restrict__ Xb,
                 const int* __restrict__ cand, const __bf16* __restrict__ Bt,
                 const float* __restrict__ bias, __bf16* __restrict__ Cout,
                 int M, int K) {
    __shared__ __bf16 smem[2 * (2048 + 8192)];   // 40 KB
    __bf16* const sA0 = smem;
    __bf16* const sA1 = smem + 2048;
    __bf16* const sB0 = smem + 4096;
    __bf16* const sB1 = smem + 4096 + 8192;

    const int bx = blockIdx.x;
    const int rblk = (bx >> 4) * 8 + (bx & 7);
    const int panel = (bx >> 3) & 1;
    const int rowBase = rblk * 64;
    if (rowBase >= M) return;                 // block-uniform, before any barrier
    const int nBase = panel * 256;

    const int tid = threadIdx.x;
    const int lane = tid & 63;
    const int wid = tid >> 6;
    const int mlane = lane & 15;
    const int quad = lane >> 4;

    const int swzc = (((lane & 3) ^ ((lane >> 3) & 3)) << 3);
    const int bRow = nBase + wid * 64 + (lane >> 2);
    const __bf16* bSrc = Bt + (size_t)bRow * K + swzc;

    const int rkey = (mlane >> 1) & 3;
    const int base_r = mlane * 32 + ((quad ^ rkey) << 3);

    const int ar = tid >> 2;
    const int acn = tid & 3;
    const int ac = acn << 3;
    const int wkey = (ar >> 1) & 3;
    const int woffA = ar * 32 + ((acn ^ wkey) << 3);

    f32x4 acc[4][4];
    #pragma unroll
    for (int i = 0; i < 4; i++)
        #pragma unroll
        for (int j = 0; j < 4; j++) acc[i][j] = f32x4{0.f, 0.f, 0.f, 0.f};

    int uu = 0, vv = 0;
    const int grow = rowBase + ar;
    const bool arowok = (grow < M);
    if (AMODE == 1 && arowok) { uu = cand[2 * grow]; vv = cand[2 * grow + 1]; }

    bf16x8 pxu{}, pxv{};
    int pk = 0;

    auto stageB = [&](__bf16* bufB, int k0) {
        #pragma unroll
        for (int j = 0; j < 4; j++)
            gload16(bSrc + (size_t)j * 16 * K + k0, bufB + wid * 2048 + j * 512);
    };
    auto issueA1 = [&](int k0) {
        pk = k0;
        if (arowok) {
            int kk = (k0 + ac) & 511;
            pxu = *(const bf16x8*)(Xb + (size_t)uu * 512 + kk);
            pxv = *(const bf16x8*)(Xb + (size_t)vv * 512 + kk);
        }
    };
    auto commitA1 = [&](__bf16* bufA) {
        bf16x8 av = bf16x8{};
        if (arowok) {
            if (pk + ac < 512) {
                #pragma unroll
                for (int q = 0; q < 8; q++) av[q] = (__bf16)((float)pxu[q] + (float)pxv[q]);
            } else {
                #pragma unroll
                for (int q = 0; q < 8; q++) av[q] = (__bf16)fabsf((float)pxu[q] - (float)pxv[q]);
            }
        }
        *(bf16x8*)(bufA + woffA) = av;
    };

    auto compute = [&](const __bf16* bufA, const __bf16* bufB) {
        bf16x8 aF[4], bF[4];
        #pragma unroll
        for (int mt = 0; mt < 4; mt++)
            aF[mt] = *(const bf16x8*)(bufA + mt * 512 + base_r);
        #pragma unroll
        for (int nt = 0; nt < 4; nt++)
            bF[nt] = *(const bf16x8*)(bufB + wid * 2048 + nt * 512 + base_r);
        #pragma unroll
        for (int mt = 0; mt < 4; mt++)
            #pragma unroll
            for (int nt = 0; nt < 4; nt++)
                acc[mt][nt] = __builtin_amdgcn_mfma_f32_16x16x32_bf16(aF[mt], bF[nt], acc[mt][nt], 0, 0, 0);
    };

    const int nt = K >> 5;
    issueA1(0);
    commitA1(sA0);
    stageB(sB0, 0);
    __syncthreads();
    for (int t = 0; t < nt; t += 2) {
        issueA1((t + 1) << 5);
        stageB(sB1, (t + 1) << 5);
        compute(sA0, sB0);
        commitA1(sA1);
        __syncthreads();
        if (t + 2 < nt) {
            issueA1((t + 2) << 5);
            stageB(sB0, (t + 2) << 5);
        }
        compute(sA1, sB1);
        if (t + 2 < nt) commitA1(sA0);
        __syncthreads();
    }

    float bv[4];
    #pragma unroll
    for (int nt2 = 0; nt2 < 4; nt2++) bv[nt2] = bias[nBase + wid * 64 + nt2 * 16 + mlane];

    float* tp = (float*)smem;
    const int erow = tid >> 4;
    const int ecg = tid & 15;
    #pragma unroll
    for (int mt = 0; mt < 4; mt++) {
        __syncthreads();
        #pragma unroll
        for (int nt2 = 0; nt2 < 4; nt2++) {
            #pragma unroll
            for (int r = 0; r < 4; r++) {
                float v = acc[mt][nt2][r] + bv[nt2];
                if (RELU) v = fmaxf(v, 0.f);
                tp[(quad * 4 + r) * 260 + wid * 64 + nt2 * 16 + mlane] = v;
            }
        }
        __syncthreads();
        int gr = rowBase + mt * 16 + erow;
        if (gr < M) {
            const float* rp = tp + erow * 260 + ecg * 16;
            f32x4 a = *(const f32x4*)(rp);
            f32x4 b = *(const f32x4*)(rp + 4);
            f32x4 c = *(const f32x4*)(rp + 8);
            f32x4 d = *(const f32x4*)(rp + 12);
            bf16x8 o0, o1;
            #pragma unroll
            for (int j = 0; j < 4; j++) { o0[j] = (__bf16)a[j]; o0[4 + j] = (__bf16)b[j]; }
            #pragma unroll
            for (int j = 0; j < 4; j++) { o1[j] = (__bf16)c[j]; o1[4 + j] = (__bf16)d[j]; }
            __bf16* op = Cout + (size_t)gr * 512 + nBase + ecg * 16;
            *(bf16x8*)op = o0;
            *(bf16x8*)(op + 8) = o1;
        }
    }
}

// ---------------- head constant vector ----------------
__global__ __launch_bounds__(512)
void constvec_kernel(const __bf16* __restrict__ xb, const int* __restrict__ first_edge,
                     const float* __restrict__ t,
                     const float* __restrict__ tw1, const float* __restrict__ tb1,
                     const float* __restrict__ tw2, const float* __restrict__ tb2,
                     const float* __restrict__ pw1, const float* __restrict__ pb1,
                     float* __restrict__ cvec) {
    __shared__ float z1[512];
    __shared__ float te[512];
    __shared__ float ff[1024];
    int tid = threadIdx.x;
    float tv = t[0];
    z1[tid] = fmaxf(tv * tw1[tid] + tb1[tid], 0.f);
    int u = first_edge[0], v = first_edge[1];
    float xu = (float)xb[(size_t)u * 512 + tid];
    float xv = (float)xb[(size_t)v * 512 + tid];
    ff[tid] = xu + xv;
    ff[512 + tid] = fabsf(xu - xv);
    __syncthreads();
    float s = tb2[tid];
    for (int j = 0; j < 512; j++) s += z1[j] * tw2[j * 512 + tid];
    te[tid] = s;
    __syncthreads();
    float c = pb1[tid];
    for (int k = 0; k < 1024; k++) c += ff[k] * pw1[k * 512 + tid];
    for (int j = 0; j < 512; j++) c += te[j] * pw1[(2048 + j) * 512 + tid];
    cvec[tid] = c;
}

// ---------------- final dot ----------------
__global__ __launch_bounds__(256)
void logits_kernel(const __bf16* __restrict__ Z, const float* __restrict__ w2,
                   const float* __restrict__ b2, float* __restrict__ out, int C) {
    int c = blockIdx.x * 4 + (threadIdx.x >> 6);
    if (c >= C) return;
    int lane = threadIdx.x & 63;
    bf16x8 z = *(const bf16x8*)(Z + (size_t)c * 512 + lane * 8);
    const float4* w = (const float4*)(w2 + lane * 8);
    float4 w0 = w[0], w1 = w[1];
    float s = (float)z[0] * w0.x + (float)z[1] * w0.y + (float)z[2] * w0.z + (float)z[3] * w0.w
            + (float)z[4] * w1.x + (float)z[5] * w1.y + (float)z[6] * w1.z + (float)z[7] * w1.w;
    #pragma unroll
    for (int off = 32; off > 0; off >>= 1) s += __shfl_down(s, off);
    if (lane == 0) out[c] = s + b2[0];
}

extern "C" void kernel_launch(void* const* d_in, const int* in_sizes, int n_in,
                              void* d_out, int out_size, void* d_ws, size_t ws_size,
                              hipStream_t stream) {
    (void)n_in; (void)out_size; (void)ws_size;
    const float* x          = (const float*)d_in[0];
    const int*   edge_index = (const int*)d_in[1];
    const int*   first_edge = (const int*)d_in[2];
    const int*   cand       = (const int*)d_in[3];
    const float* t          = (const float*)d_in[4];
    const float* gw1[3] = {(const float*)d_in[5], (const float*)d_in[9],  (const float*)d_in[13]};
    const float* gb1[3] = {(const float*)d_in[6], (const float*)d_in[10], (const float*)d_in[14]};
    const float* gw2[3] = {(const float*)d_in[7], (const float*)d_in[11], (const float*)d_in[15]};
    const float* gb2[3] = {(const float*)d_in[8], (const float*)d_in[12], (const float*)d_in[16]};
    const float* pw1 = (const float*)d_in[17];
    const float* pb1 = (const float*)d_in[18];
    const float* pw2 = (const float*)d_in[19];
    const float* pb2 = (const float*)d_in[20];
    const float* tw1 = (const float*)d_in[21];
    const float* tb1 = (const float*)d_in[22];
    const float* tw2 = (const float*)d_in[23];
    const float* tb2 = (const float*)d_in[24];

    const int N = in_sizes[0] / 128;   // 50000
    const int E = in_sizes[1] / 2;     // 1600000
    const int C = in_sizes[3] / 2;     // 50000

    char* p = (char*)d_ws;
    auto alloc = [&](size_t bytes) -> void* {
        void* r = (void*)p;
        p += (bytes + 255) & ~(size_t)255;
        return r;
    };
    __bf16* h    = (__bf16*)alloc((size_t)N * 512 * 2);
    __bf16* u    = (__bf16*)alloc((size_t)N * 512 * 2);  // xb0 alias pre-L0; Z for head
    __bf16* xb   = (__bf16*)alloc((size_t)N * 512 * 2);
    __bf16* wt01 = (__bf16*)alloc((size_t)512 * 128 * 2);
    __bf16* wt02 = (__bf16*)alloc((size_t)512 * 512 * 2);
    __bf16* wt11 = (__bf16*)alloc((size_t)512 * 512 * 2);
    __bf16* wt12 = (__bf16*)alloc((size_t)512 * 512 * 2);
    __bf16* wt21 = (__bf16*)alloc((size_t)512 * 512 * 2);
    __bf16* wt22 = (__bf16*)alloc((size_t)512 * 512 * 2);
    __bf16* wtH  = (__bf16*)alloc((size_t)512 * 1024 * 2);
    int* rowptr = (int*)alloc((size_t)(N + 1) * 4);
    int* deg    = (int*)alloc((size_t)N * 4);
    int* cursor = (int*)alloc((size_t)N * 4);
    int* colsrc = (int*)alloc((size_t)E * 4);
    int* bsum   = (int*)alloc((size_t)256 * 4);
    float* cvec = (float*)alloc(512 * 4);
    __bf16* xb0 = (__bf16*)u;   // alias: xb0 dead before u is first written (head)

    const int* src = edge_index;
    const int* dst = edge_index + E;

    // CSR build (XCD-partitioned hist + scatter)
    hipMemsetAsync(deg, 0, (size_t)N * 4, stream);
    int nb = (N + 255) / 256;
    hist_part_kernel<<<CSR_CHUNKS * 8, 256, 0, stream>>>(dst, deg, E, N);
    blocksum_kernel<<<nb, 256, 0, stream>>>(deg, bsum, N);
    scanb_kernel<<<1, 256, 0, stream>>>(bsum, nb);
    scanw_kernel<<<nb, 256, 0, stream>>>(deg, bsum, rowptr, cursor, N);
    scatter_part_kernel<<<CSR_CHUNKS * 8, 256, 0, stream>>>(src, dst, cursor, colsrc, E, N);

    // input + weight prep
    f32_to_bf16_kernel<<<((N * 128 / 4) + 255) / 256, 256, 0, stream>>>(x, xb0, N * 128 / 4);
    wprep_kernel<<<((512 << 7)  + 255) / 256, 256, 0, stream>>>(gw1[0], wt01, 7);
    wprep_kernel<<<((512 << 9)  + 255) / 256, 256, 0, stream>>>(gw2[0], wt02, 9);
    wprep_kernel<<<((512 << 9)  + 255) / 256, 256, 0, stream>>>(gw1[1], wt11, 9);
    wprep_kernel<<<((512 << 9)  + 255) / 256, 256, 0, stream>>>(gw2[1], wt12, 9);
    wprep_kernel<<<((512 << 9)  + 255) / 256, 256, 0, stream>>>(gw1[2], wt21, 9);
    wprep_kernel<<<((512 << 9)  + 255) / 256, 256, 0, stream>>>(gw2[2], wt22, 9);
    wprep_kernel<<<((512 << 10) + 255) / 256, 256, 0, stream>>>(pw1 + (size_t)1024 * 512, wtH, 10);

    const int Rblk = (N + 63) / 64;                 // 782
    const int gpair = ((Rblk + 7) / 8) * 16;        // head grid (paired panels)
    int ablocks = (N + 3) / 4;

    // layer 0 (D=128): fused h@w1+relu -> u(LDS) -> u@w2 -> xb
    agg_kernel<2, 16, 128><<<ablocks, 256, 0, stream>>>(xb0, rowptr, colsrc, h, N, 0);
    layer_kernel<0><<<Rblk, 512, 0, stream>>>(h, wt01, gb1[0], wt02, gb2[0], xb, N, 128);
    // layer 1
    agg_kernel<4, 8, 512><<<ablocks, 256, 0, stream>>>(xb, rowptr, colsrc, h, N, 0);
    agg_kernel<4, 8, 512><<<ablocks, 256, 0, stream>>>(xb, rowptr, colsrc, h, N, 256);
    layer_kernel<0><<<Rblk, 512, 0, stream>>>(h, wt11, gb1[1], wt12, gb2[1], xb, N, 512);
    // layer 2
    agg_kernel<4, 8, 512><<<ablocks, 256, 0, stream>>>(xb, rowptr, colsrc, h, N, 0);
    agg_kernel<4, 8, 512><<<ablocks, 256, 0, stream>>>(xb, rowptr, colsrc, h, N, 256);
    layer_kernel<0><<<Rblk, 512, 0, stream>>>(h, wt21, gb1[2], wt22, gb2[2], xb, N, 512);

    // prediction head
    constvec_kernel<<<1, 512, 0, stream>>>(xb, first_edge, t, tw1, tb1, tw2, tb2, pw1, pb1, cvec);
    gemm_kernel<1, true><<<gpair, 256, 0, stream>>>(nullptr, xb, cand, wtH, cvec, u, C, 1024);
    logits_kernel<<<(C + 3) / 4, 256, 0, stream>>>(u, pw2, pb2, (float*)d_out, C);
}

// Round 16
// 1189.230 us; speedup vs baseline: 1.0339x; 1.0339x over previous
//
#include <hip/hip_runtime.h>

typedef __bf16 bf16x2 __attribute__((ext_vector_type(2)));
typedef __bf16 bf16x4 __attribute__((ext_vector_type(4)));
typedef __bf16 bf16x8 __attribute__((ext_vector_type(8)));
typedef float f32x4 __attribute__((ext_vector_type(4)));

#define CSR_CHUNKS 256  // edge stripes per dst-range in partitioned CSR build

__device__ __forceinline__ void gload16(const __bf16* g, __bf16* l) {
    __builtin_amdgcn_global_load_lds((const __attribute__((address_space(1))) void*)g,
                                     (__attribute__((address_space(3))) void*)l, 16, 0, 0);
}

// ---------------- CSR build (XCD-partitioned by dst range) ----------------
__global__ __launch_bounds__(256)
void hist_part_kernel(const int* __restrict__ dst, int* __restrict__ deg, int E, int N) {
    const int r = blockIdx.x & 7;
    const int chunk = blockIdx.x >> 3;
    const int RS = (N + 7) >> 3;
    const int lo = r * RS;
    const int hi = min(lo + RS, N);
    const int stride = CSR_CHUNKS * 256;
    for (int i = chunk * 256 + threadIdx.x; i < E; i += stride) {
        int d = dst[i];
        if (d >= lo && d < hi) atomicAdd(&deg[d], 1);
    }
}

__global__ __launch_bounds__(256)
void scatter_part_kernel(const int* __restrict__ src, const int* __restrict__ dst,
                         int* __restrict__ cursor, int* __restrict__ colsrc, int E, int N) {
    const int r = blockIdx.x & 7;
    const int chunk = blockIdx.x >> 3;
    const int RS = (N + 7) >> 3;
    const int lo = r * RS;
    const int hi = min(lo + RS, N);
    const int stride = CSR_CHUNKS * 256;
    for (int i = chunk * 256 + threadIdx.x; i < E; i += stride) {
        int d = dst[i];
        if (d >= lo && d < hi) {
            int p = atomicAdd(&cursor[d], 1);
            colsrc[p] = src[i];
        }
    }
}

// hierarchical exclusive scan of deg -> rowptr/cursor
__global__ __launch_bounds__(256)
void blocksum_kernel(const int* __restrict__ deg, int* __restrict__ bsum, int n) {
    __shared__ int red[256];
    int i = blockIdx.x * 256 + threadIdx.x;
    red[threadIdx.x] = (i < n) ? deg[i] : 0;
    __syncthreads();
    for (int off = 128; off > 0; off >>= 1) {
        if (threadIdx.x < off) red[threadIdx.x] += red[threadIdx.x + off];
        __syncthreads();
    }
    if (threadIdx.x == 0) bsum[blockIdx.x] = red[0];
}

__global__ __launch_bounds__(256)
void scanb_kernel(int* __restrict__ bsum, int nb) {
    __shared__ int s[256];
    int t = threadIdx.x;
    s[t] = (t < nb) ? bsum[t] : 0;
    __syncthreads();
    for (int off = 1; off < 256; off <<= 1) {
        int v = (t >= off) ? s[t - off] : 0;
        __syncthreads();
        s[t] += v;
        __syncthreads();
    }
    if (t < nb) bsum[t] = (t == 0) ? 0 : s[t - 1];
}

__global__ __launch_bounds__(256)
void scanw_kernel(const int* __restrict__ deg, const int* __restrict__ bsum,
                  int* __restrict__ rowptr, int* __restrict__ cursor, int n) {
    __shared__ int s[256];
    int b = blockIdx.x, t = threadIdx.x;
    int i = b * 256 + t;
    int d = (i < n) ? deg[i] : 0;
    s[t] = d;
    __syncthreads();
    for (int off = 1; off < 256; off <<= 1) {
        int v = (t >= off) ? s[t - off] : 0;
        __syncthreads();
        s[t] += v;
        __syncthreads();
    }
    int incl = s[t];
    int base = bsum[b];
    if (i < n) {
        int r = base + incl - d;
        rowptr[i] = r;
        cursor[i] = r;
        if (i == n - 1) rowptr[n] = base + incl;
    }
}

// ---------------- dtype convert / weight prep ----------------
__global__ void f32_to_bf16_kernel(const float* __restrict__ in, __bf16* __restrict__ out, int n4) {
    int i = blockIdx.x * 256 + threadIdx.x;
    if (i < n4) {
        float4 f = ((const float4*)in)[i];
        bf16x4 o;
        o[0] = (__bf16)f.x; o[1] = (__bf16)f.y; o[2] = (__bf16)f.z; o[3] = (__bf16)f.w;
        ((bf16x4*)out)[i] = o;
    }
}

__global__ void wprep_kernel(const float* __restrict__ in, __bf16* __restrict__ out, int kbits) {
    int idx = blockIdx.x * 256 + threadIdx.x;
    int K = 1 << kbits;
    if (idx < (512 << kbits)) {
        int k = idx & (K - 1);
        int n = idx >> kbits;
        out[idx] = (__bf16)in[k * 512 + n];
    }
}

// ---------------- aggregation ----------------
template<int F> struct VecT;
template<> struct VecT<2> { using T = bf16x2; };
template<> struct VecT<4> { using T = bf16x4; };
template<> struct VecT<8> { using T = bf16x8; };

template<int F, int U, int STR>
__global__ __launch_bounds__(256)
void agg_kernel(const __bf16* __restrict__ xb, const int* __restrict__ rowptr,
                const int* __restrict__ colsrc, __bf16* __restrict__ h, int n, int colbase) {
    const int node = blockIdx.x * 4 + (threadIdx.x >> 6);
    if (node >= n) return;
    const int lane = threadIdx.x & 63;
    using V = typename VecT<F>::T;

    const __bf16* xl = xb + colbase + lane * F;

    float acc[F];
    {
        V v = *(const V*)(xl + (size_t)node * STR);
        #pragma unroll
        for (int i = 0; i < F; i++) acc[i] = (float)v[i];
    }

    int e   = __builtin_amdgcn_readfirstlane(rowptr[node]);
    int end = __builtin_amdgcn_readfirstlane(rowptr[node + 1]);

    for (; e + U <= end; e += U) {
        int s[U];
        #pragma unroll
        for (int j = 0; j < U; j++) s[j] = colsrc[e + j];
        V v[U];
        #pragma unroll
        for (int j = 0; j < U; j++) v[j] = *(const V*)(xl + (size_t)s[j] * STR);
        #pragma unroll
        for (int j = 0; j < U; j++)
            #pragma unroll
            for (int i = 0; i < F; i++) acc[i] += (float)v[j][i];
    }
    if constexpr (U > 4) {
        for (; e + 4 <= end; e += 4) {
            int s[4];
            #pragma unroll
            for (int j = 0; j < 4; j++) s[j] = colsrc[e + j];
            V v[4];
            #pragma unroll
            for (int j = 0; j < 4; j++) v[j] = *(const V*)(xl + (size_t)s[j] * STR);
            #pragma unroll
            for (int j = 0; j < 4; j++)
                #pragma unroll
                for (int i = 0; i < F; i++) acc[i] += (float)v[j][i];
        }
    }
    for (; e < end; e++) {
        int s0 = colsrc[e];
        V v = *(const V*)(xl + (size_t)s0 * STR);
        #pragma unroll
        for (int i = 0; i < F; i++) acc[i] += (float)v[i];
    }

    __bf16* out = h + colbase + (size_t)node * STR + lane * F;
    V o;
    #pragma unroll
    for (int i = 0; i < F; i++) o[i] = (__bf16)acc[i];
    *(V*)out = o;
}

// ---------------- MFMA GEMM: out = epilogue(A @ Bt^T + bias) ----------------
// Tile 64(M) x 256(N), 4 waves, each wave 64x64 (4x4 frags, 16 MFMA/step).
// 1D grid with SAME-XCD PANEL PAIRING: bx = 16q + 8p + s -> row-block r = 8q+s,
// N-panel p. Both panels of a row share bx%8 (same XCD under round-robin
// dispatch) and run ~simultaneously -> panel 1's A reads (and head's Xb
// gathers) hit that XCD's L2 instead of re-fetching from HBM (R12 showed
// FETCH = 2xA + B from the grid.y split).
// AMODE 0: DMA staging (global_load_lds w16, source-swizzled) with counted
// vmcnt (never 0 in steady state). AMODE 1: compiler-managed dbuf (gather-A).
template<int AMODE, bool RELU>
__global__ __launch_bounds__(256, 3)
void gemm_kernel(const __bf16* __restrict__ A, const __bf16* __restrict__ Xb,
                 const int* __restrict__ cand, const __bf16* __restrict__ Bt,
                 const float* __restrict__ bias, __bf16* __restrict__ Cout,
                 int M, int K) {
    __shared__ __bf16 smem[2 * (2048 + 8192)];   // 40 KB: sA0 sA1 sB0 sB1
    __bf16* const sA0 = smem;
    __bf16* const sA1 = smem + 2048;
    __bf16* const sB0 = smem + 4096;
    __bf16* const sB1 = smem + 4096 + 8192;

    // same-XCD panel pairing decode
    const int bx = blockIdx.x;
    const int rblk = (bx >> 4) * 8 + (bx & 7);
    const int panel = (bx >> 3) & 1;
    const int rowBase = rblk * 64;
    if (rowBase >= M) return;                 // block-uniform, before any barrier
    const int nBase = panel * 256;

    const int tid = threadIdx.x;
    const int lane = tid & 63;
    const int wid = tid >> 6;
    const int mlane = lane & 15;
    const int quad = lane >> 4;

    // per-lane swizzled source column offset within each 32-elem K-chunk
    const int swzc = (((lane & 3) ^ ((lane >> 3) & 3)) << 3);

    // A DMA staging (AMODE 0): wave w stages rows [w*16, w*16+16); row CLAMPED so
    // every wave issues exactly 1 A-DMA (uniform vmcnt); OOB rows masked at store.
    const int aRow = rowBase + wid * 16 + (lane >> 2);
    const int aRowC = (aRow < M) ? aRow : (M - 1);
    const __bf16* aSrc = A + (size_t)aRowC * K + swzc;      // valid only AMODE 0
    // B DMA staging: wave w, call j stages rows nBase + w*64 + j*16 + (l>>2)
    const int bRow = nBase + wid * 64 + (lane >> 2);
    const __bf16* bSrc = Bt + (size_t)bRow * K + swzc;

    // read-side swizzle (R8-verified conflict-free)
    const int rkey = (mlane >> 1) & 3;
    const int base_r = mlane * 32 + ((quad ^ rkey) << 3);

    // AMODE 1 A reg-staging geometry
    const int ar = tid >> 2;
    const int acn = tid & 3;
    const int ac = acn << 3;
    const int wkey = (ar >> 1) & 3;
    const int woffA = ar * 32 + ((acn ^ wkey) << 3);

    f32x4 acc[4][4];
    #pragma unroll
    for (int i = 0; i < 4; i++)
        #pragma unroll
        for (int j = 0; j < 4; j++) acc[i][j] = f32x4{0.f, 0.f, 0.f, 0.f};

    int uu = 0, vv = 0;
    const int grow = rowBase + ar;
    const bool arowok = (grow < M);
    if (AMODE == 1 && arowok) { uu = cand[2 * grow]; vv = cand[2 * grow + 1]; }

    bf16x8 pxu{}, pxv{};
    int pk = 0;

    auto stageB = [&](__bf16* bufB, int k0) {
        #pragma unroll
        for (int j = 0; j < 4; j++)
            gload16(bSrc + (size_t)j * 16 * K + k0, bufB + wid * 2048 + j * 512);
    };
    auto stageA0 = [&](__bf16* bufA, int k0) {
        gload16(aSrc + k0, bufA + wid * 512);
    };
    auto issueA1 = [&](int k0) {
        pk = k0;
        if (arowok) {
            int kk = (k0 + ac) & 511;   // chunk of 8 never crosses the 512 boundary
            pxu = *(const bf16x8*)(Xb + (size_t)uu * 512 + kk);
            pxv = *(const bf16x8*)(Xb + (size_t)vv * 512 + kk);
        }
    };
    auto commitA1 = [&](__bf16* bufA) {
        bf16x8 av = bf16x8{};
        if (arowok) {
            if (pk + ac < 512) {
                #pragma unroll
                for (int q = 0; q < 8; q++) av[q] = (__bf16)((float)pxu[q] + (float)pxv[q]);
            } else {
                #pragma unroll
                for (int q = 0; q < 8; q++) av[q] = (__bf16)fabsf((float)pxu[q] - (float)pxv[q]);
            }
        }
        *(bf16x8*)(bufA + woffA) = av;
    };

    auto compute = [&](const __bf16* bufA, const __bf16* bufB) {
        bf16x8 aF[4], bF[4];
        #pragma unroll
        for (int mt = 0; mt < 4; mt++)
            aF[mt] = *(const bf16x8*)(bufA + mt * 512 + base_r);
        #pragma unroll
        for (int nt = 0; nt < 4; nt++)
            bF[nt] = *(const bf16x8*)(bufB + wid * 2048 + nt * 512 + base_r);
        #pragma unroll
        for (int mt = 0; mt < 4; mt++)
            #pragma unroll
            for (int nt = 0; nt < 4; nt++)
                acc[mt][nt] = __builtin_amdgcn_mfma_f32_16x16x32_bf16(aF[mt], bF[nt], acc[mt][nt], 0, 0, 0);
    };

    const int nt = K >> 5;              // K-tiles; always even (4/16/32)
    if (AMODE == 0) {
        // prologue: two tiles issued, wait only for the first (counted)
        stageA0(sA0, 0);
        stageB(sB0, 0);
        __builtin_amdgcn_sched_barrier(0);      // pin issue order: tile0 before tile1
        stageA0(sA1, 32);
        stageB(sB1, 32);
        asm volatile("s_waitcnt vmcnt(5)" ::: "memory");   // tile0's 5 landed
        __builtin_amdgcn_s_barrier();
        __builtin_amdgcn_sched_barrier(0);

        int cur = 0;
        for (int t = 0; t < nt; ++t) {
            __bf16* cA = cur ? sA1 : sA0;
            __bf16* cB = cur ? sB1 : sB0;
            compute(cA, cB);
            if (t + 1 < nt) {
                __builtin_amdgcn_s_barrier();           // all readers of buf[cur] done
                __builtin_amdgcn_sched_barrier(0);
                if (t + 2 < nt) {
                    stageA0(cA, (t + 2) << 5);          // 5 DMA into just-freed buffer
                    stageB(cB, (t + 2) << 5);
                    asm volatile("s_waitcnt vmcnt(5)" ::: "memory");  // t+1 ready; t+2 in flight
                } else {
                    asm volatile("s_waitcnt vmcnt(0)" ::: "memory");  // final drain
                }
                __builtin_amdgcn_s_barrier();
                __builtin_amdgcn_sched_barrier(0);
                cur ^= 1;
            }
        }
    } else {
        issueA1(0);
        commitA1(sA0);
        stageB(sB0, 0);
        __syncthreads();
        for (int t = 0; t < nt; t += 2) {
            issueA1((t + 1) << 5);
            stageB(sB1, (t + 1) << 5);
            compute(sA0, sB0);
            commitA1(sA1);
            __syncthreads();
            if (t + 2 < nt) {
                issueA1((t + 2) << 5);
                stageB(sB0, (t + 2) << 5);
            }
            compute(sA1, sB1);
            if (t + 2 < nt) commitA1(sA0);
            __syncthreads();
        }
    }

    // ---- epilogue: LDS transpose (f32, stride 260) -> coalesced bf16x8 stores ----
    float bv[4];
    #pragma unroll
    for (int nt2 = 0; nt2 < 4; nt2++) bv[nt2] = bias[nBase + wid * 64 + nt2 * 16 + mlane];

    float* tp = (float*)smem;           // 16 x 260 f32 = 16.6 KB, fits in 40 KB
    const int erow = tid >> 4;          // 0..15
    const int ecg = tid & 15;           // col group of 16
    #pragma unroll
    for (int mt = 0; mt < 4; mt++) {
        __syncthreads();
        #pragma unroll
        for (int nt2 = 0; nt2 < 4; nt2++) {
            #pragma unroll
            for (int r = 0; r < 4; r++) {
                float v = acc[mt][nt2][r] + bv[nt2];
                if (RELU) v = fmaxf(v, 0.f);
                tp[(quad * 4 + r) * 260 + wid * 64 + nt2 * 16 + mlane] = v;
            }
        }
        __syncthreads();
        int gr = rowBase + mt * 16 + erow;
        if (gr < M) {
            const float* rp = tp + erow * 260 + ecg * 16;
            f32x4 a = *(const f32x4*)(rp);
            f32x4 b = *(const f32x4*)(rp + 4);
            f32x4 c = *(const f32x4*)(rp + 8);
            f32x4 d = *(const f32x4*)(rp + 12);
            bf16x8 o0, o1;
            #pragma unroll
            for (int j = 0; j < 4; j++) { o0[j] = (__bf16)a[j]; o0[4 + j] = (__bf16)b[j]; }
            #pragma unroll
            for (int j = 0; j < 4; j++) { o1[j] = (__bf16)c[j]; o1[4 + j] = (__bf16)d[j]; }
            __bf16* op = Cout + (size_t)gr * 512 + nBase + ecg * 16;
            *(bf16x8*)op = o0;
            *(bf16x8*)(op + 8) = o1;
        }
    }
}

// ---------------- head constant vector ----------------
__global__ __launch_bounds__(512)
void constvec_kernel(const __bf16* __restrict__ xb, const int* __restrict__ first_edge,
                     const float* __restrict__ t,
                     const float* __restrict__ tw1, const float* __restrict__ tb1,
                     const float* __restrict__ tw2, const float* __restrict__ tb2,
                     const float* __restrict__ pw1, const float* __restrict__ pb1,
                     float* __restrict__ cvec) {
    __shared__ float z1[512];
    __shared__ float te[512];
    __shared__ float ff[1024];
    int tid = threadIdx.x;
    float tv = t[0];
    z1[tid] = fmaxf(tv * tw1[tid] + tb1[tid], 0.f);
    int u = first_edge[0], v = first_edge[1];
    float xu = (float)xb[(size_t)u * 512 + tid];
    float xv = (float)xb[(size_t)v * 512 + tid];
    ff[tid] = xu + xv;
    ff[512 + tid] = fabsf(xu - xv);
    __syncthreads();
    float s = tb2[tid];
    for (int j = 0; j < 512; j++) s += z1[j] * tw2[j * 512 + tid];
    te[tid] = s;
    __syncthreads();
    float c = pb1[tid];
    for (int k = 0; k < 1024; k++) c += ff[k] * pw1[k * 512 + tid];
    for (int j = 0; j < 512; j++) c += te[j] * pw1[(2048 + j) * 512 + tid];
    cvec[tid] = c;
}

// ---------------- final dot ----------------
__global__ __launch_bounds__(256)
void logits_kernel(const __bf16* __restrict__ Z, const float* __restrict__ w2,
                   const float* __restrict__ b2, float* __restrict__ out, int C) {
    int c = blockIdx.x * 4 + (threadIdx.x >> 6);
    if (c >= C) return;
    int lane = threadIdx.x & 63;
    bf16x8 z = *(const bf16x8*)(Z + (size_t)c * 512 + lane * 8);
    const float4* w = (const float4*)(w2 + lane * 8);
    float4 w0 = w[0], w1 = w[1];
    float s = (float)z[0] * w0.x + (float)z[1] * w0.y + (float)z[2] * w0.z + (float)z[3] * w0.w
            + (float)z[4] * w1.x + (float)z[5] * w1.y + (float)z[6] * w1.z + (float)z[7] * w1.w;
    #pragma unroll
    for (int off = 32; off > 0; off >>= 1) s += __shfl_down(s, off);
    if (lane == 0) out[c] = s + b2[0];
}

extern "C" void kernel_launch(void* const* d_in, const int* in_sizes, int n_in,
                              void* d_out, int out_size, void* d_ws, size_t ws_size,
                              hipStream_t stream) {
    (void)n_in; (void)out_size; (void)ws_size;
    const float* x          = (const float*)d_in[0];
    const int*   edge_index = (const int*)d_in[1];
    const int*   first_edge = (const int*)d_in[2];
    const int*   cand       = (const int*)d_in[3];
    const float* t          = (const float*)d_in[4];
    const float* gw1[3] = {(const float*)d_in[5], (const float*)d_in[9],  (const float*)d_in[13]};
    const float* gb1[3] = {(const float*)d_in[6], (const float*)d_in[10], (const float*)d_in[14]};
    const float* gw2[3] = {(const float*)d_in[7], (const float*)d_in[11], (const float*)d_in[15]};
    const float* gb2[3] = {(const float*)d_in[8], (const float*)d_in[12], (const float*)d_in[16]};
    const float* pw1 = (const float*)d_in[17];
    const float* pb1 = (const float*)d_in[18];
    const float* pw2 = (const float*)d_in[19];
    const float* pb2 = (const float*)d_in[20];
    const float* tw1 = (const float*)d_in[21];
    const float* tb1 = (const float*)d_in[22];
    const float* tw2 = (const float*)d_in[23];
    const float* tb2 = (const float*)d_in[24];

    const int N = in_sizes[0] / 128;   // 50000
    const int E = in_sizes[1] / 2;     // 1600000
    const int C = in_sizes[3] / 2;     // 50000

    char* p = (char*)d_ws;
    auto alloc = [&](size_t bytes) -> void* {
        void* r = (void*)p;
        p += (bytes + 255) & ~(size_t)255;
        return r;
    };
    __bf16* h    = (__bf16*)alloc((size_t)N * 512 * 2);
    __bf16* u    = (__bf16*)alloc((size_t)N * 512 * 2);  // also aliases xb0 pre-L0, and Z for head
    __bf16* xb   = (__bf16*)alloc((size_t)N * 512 * 2);
    __bf16* wt01 = (__bf16*)alloc((size_t)512 * 128 * 2);
    __bf16* wt02 = (__bf16*)alloc((size_t)512 * 512 * 2);
    __bf16* wt11 = (__bf16*)alloc((size_t)512 * 512 * 2);
    __bf16* wt12 = (__bf16*)alloc((size_t)512 * 512 * 2);
    __bf16* wt21 = (__bf16*)alloc((size_t)512 * 512 * 2);
    __bf16* wt22 = (__bf16*)alloc((size_t)512 * 512 * 2);
    __bf16* wtH  = (__bf16*)alloc((size_t)512 * 1024 * 2);
    int* rowptr = (int*)alloc((size_t)(N + 1) * 4);
    int* deg    = (int*)alloc((size_t)N * 4);
    int* cursor = (int*)alloc((size_t)N * 4);
    int* colsrc = (int*)alloc((size_t)E * 4);
    int* bsum   = (int*)alloc((size_t)256 * 4);
    float* cvec = (float*)alloc(512 * 4);
    __bf16* xb0 = (__bf16*)u;   // alias: xb0 dead before u is first written (L0 gemm1)

    const int* src = edge_index;
    const int* dst = edge_index + E;

    // CSR build (XCD-partitioned hist + scatter)
    hipMemsetAsync(deg, 0, (size_t)N * 4, stream);
    int nb = (N + 255) / 256;
    hist_part_kernel<<<CSR_CHUNKS * 8, 256, 0, stream>>>(dst, deg, E, N);
    blocksum_kernel<<<nb, 256, 0, stream>>>(deg, bsum, N);
    scanb_kernel<<<1, 256, 0, stream>>>(bsum, nb);
    scanw_kernel<<<nb, 256, 0, stream>>>(deg, bsum, rowptr, cursor, N);
    scatter_part_kernel<<<CSR_CHUNKS * 8, 256, 0, stream>>>(src, dst, cursor, colsrc, E, N);

    // input + weight prep
    f32_to_bf16_kernel<<<((N * 128 / 4) + 255) / 256, 256, 0, stream>>>(x, xb0, N * 128 / 4);
    wprep_kernel<<<((512 << 7)  + 255) / 256, 256, 0, stream>>>(gw1[0], wt01, 7);
    wprep_kernel<<<((512 << 9)  + 255) / 256, 256, 0, stream>>>(gw2[0], wt02, 9);
    wprep_kernel<<<((512 << 9)  + 255) / 256, 256, 0, stream>>>(gw1[1], wt11, 9);
    wprep_kernel<<<((512 << 9)  + 255) / 256, 256, 0, stream>>>(gw2[1], wt12, 9);
    wprep_kernel<<<((512 << 9)  + 255) / 256, 256, 0, stream>>>(gw1[2], wt21, 9);
    wprep_kernel<<<((512 << 9)  + 255) / 256, 256, 0, stream>>>(gw2[2], wt22, 9);
    wprep_kernel<<<((512 << 10) + 255) / 256, 256, 0, stream>>>(pw1 + (size_t)1024 * 512, wtH, 10);

    // same-XCD panel-paired 1D grid: bx = 16q + 8p + s, row = 8q+s, panel = p
    const int Rblk = (N + 63) / 64;                 // 782 row-blocks (N == C here)
    const int gpair = ((Rblk + 7) / 8) * 16;        // 1568 (4 idle tail blocks)
    int ablocks = (N + 3) / 4;

    // layer 0 (D=128)
    agg_kernel<2, 16, 128><<<ablocks, 256, 0, stream>>>(xb0, rowptr, colsrc, h, N, 0);
    gemm_kernel<0, true ><<<gpair, 256, 0, stream>>>(h, nullptr, nullptr, wt01, gb1[0], u,  N, 128);
    gemm_kernel<0, false><<<gpair, 256, 0, stream>>>(u, nullptr, nullptr, wt02, gb2[0], xb, N, 512);
    // layer 1 (column-phased gather)
    agg_kernel<4, 8, 512><<<ablocks, 256, 0, stream>>>(xb, rowptr, colsrc, h, N, 0);
    agg_kernel<4, 8, 512><<<ablocks, 256, 0, stream>>>(xb, rowptr, colsrc, h, N, 256);
    gemm_kernel<0, true ><<<gpair, 256, 0, stream>>>(h, nullptr, nullptr, wt11, gb1[1], u,  N, 512);
    gemm_kernel<0, false><<<gpair, 256, 0, stream>>>(u, nullptr, nullptr, wt12, gb2[1], xb, N, 512);
    // layer 2
    agg_kernel<4, 8, 512><<<ablocks, 256, 0, stream>>>(xb, rowptr, colsrc, h, N, 0);
    agg_kernel<4, 8, 512><<<ablocks, 256, 0, stream>>>(xb, rowptr, colsrc, h, N, 256);
    gemm_kernel<0, true ><<<gpair, 256, 0, stream>>>(h, nullptr, nullptr, wt21, gb1[2], u,  N, 512);
    gemm_kernel<0, false><<<gpair, 256, 0, stream>>>(u, nullptr, nullptr, wt22, gb2[2], xb, N, 512);

    // prediction head
    constvec_kernel<<<1, 512, 0, stream>>>(xb, first_edge, t, tw1, tb1, tw2, tb2, pw1, pb1, cvec);
    gemm_kernel<1, true><<<gpair, 256, 0, stream>>>(nullptr, xb, cand, wtH, cvec, u, C, 1024);
    logits_kernel<<<(C + 3) / 4, 256, 0, stream>>>(u, pw2, pb2, (float*)d_out, C);
}